// Round 2
// baseline (35149.640 us; speedup 1.0000x reference)
//
#include <hip/hip_runtime.h>
#include <math.h>

#define EPS 1e-5f

__device__ __forceinline__ float sgnf(float w) {
    return (w > 0.f) ? 1.f : ((w < 0.f) ? -1.f : 0.f);
}

// One thread per output pixel (pooled pixel when POOL).
// Computes relu(bn(conv(x, sign(w)) + bias)) and optional 2x2 maxpool.
template<int CI, bool POOL>
__global__ void conv_bn_relu_kernel(
    const float* __restrict__ x, const float* __restrict__ w,
    const float* __restrict__ bias, const float* __restrict__ g,
    const float* __restrict__ be, const float* __restrict__ m,
    const float* __restrict__ v,
    float* __restrict__ y,
    int B, int CO, int IH, int IW)
{
    const int OH = IH - 2, OW = IW - 2;
    const int PH = POOL ? OH / 2 : OH;
    const int PW = POOL ? OW / 2 : OW;

    long long idx = (long long)blockIdx.x * blockDim.x + threadIdx.x;
    long long total = (long long)B * CO * PH * PW;
    if (idx >= total) return;

    int pw = (int)(idx % PW); long long t = idx / PW;
    int ph = (int)(t % PH); t /= PH;
    int co = (int)(t % CO);
    int b  = (int)(t / CO);

    // folded BN affine (conv bias absorbed): y = conv*scale + shift
    float scale = g[co] * rsqrtf(v[co] + EPS);
    float shift = be[co] - m[co] * scale + bias[co] * scale;

    const float* wp = w + (long long)co * CI * 9;
    const float* xb = x + (long long)b * CI * IH * IW;

    float result = 0.f;
    #pragma unroll
    for (int dy = 0; dy < (POOL ? 2 : 1); ++dy) {
        #pragma unroll
        for (int dx = 0; dx < (POOL ? 2 : 1); ++dx) {
            const int oh = POOL ? (2 * ph + dy) : ph;
            const int ow = POOL ? (2 * pw + dx) : pw;
            float acc = 0.f;
            #pragma unroll 2
            for (int ci = 0; ci < CI; ++ci) {
                const float* xp = xb + ((long long)ci * IH + oh) * IW + ow;
                const float* wq = wp + ci * 9;
                #pragma unroll
                for (int kh = 0; kh < 3; ++kh) {
                    #pragma unroll
                    for (int kw = 0; kw < 3; ++kw) {
                        acc += xp[kh * IW + kw] * sgnf(wq[kh * 3 + kw]);
                    }
                }
            }
            float val = fmaxf(acc * scale + shift, 0.f);
            if (dy == 0 && dx == 0) result = val;
            else result = fmaxf(result, val);
        }
    }
    y[idx] = result;
}

// y[b][o] = relu?( x[b] . sign(w[o]) + bias[o] )
__global__ void fc_kernel(const float* __restrict__ x, const float* __restrict__ w,
                          const float* __restrict__ bias, float* __restrict__ y,
                          int B, int IN, int OUT, int do_relu)
{
    int idx = blockIdx.x * blockDim.x + threadIdx.x;
    if (idx >= B * OUT) return;
    int o = idx % OUT, b = idx / OUT;
    const float* xp = x + (long long)b * IN;
    const float* wp = w + (long long)o * IN;
    float acc = bias[o];
    #pragma unroll 4
    for (int k = 0; k < IN; ++k) acc += xp[k] * sgnf(wp[k]);
    y[idx] = do_relu ? fmaxf(acc, 0.f) : acc;
}

__global__ void softmax10_kernel(const float* __restrict__ logits,
                                 float* __restrict__ out, int B)
{
    int b = blockIdx.x * blockDim.x + threadIdx.x;
    if (b >= B) return;
    float l[10];
    float mx = -1e30f;
    #pragma unroll
    for (int i = 0; i < 10; ++i) { l[i] = logits[b * 10 + i]; mx = fmaxf(mx, l[i]); }
    float s = 0.f;
    #pragma unroll
    for (int i = 0; i < 10; ++i) { l[i] = __expf(l[i] - mx); s += l[i]; }
    float r = 1.f / s;
    #pragma unroll
    for (int i = 0; i < 10; ++i) out[b * 10 + i] = l[i] * r;
}

static inline int cdiv_ll(long long a, int b) { return (int)((a + b - 1) / b); }

extern "C" void kernel_launch(void* const* d_in, const int* in_sizes, int n_in,
                              void* d_out, int out_size, void* d_ws, size_t ws_size,
                              hipStream_t stream) {
    const int B = 512;
    const float* x = (const float*)d_in[0];
    // layer i (1-based): base = 1 + (i-1)*6 : w, b, g, be, m, v
    auto W  = [&](int i) { return (const float*)d_in[1 + (i - 1) * 6 + 0]; };
    auto Bi = [&](int i) { return (const float*)d_in[1 + (i - 1) * 6 + 1]; };
    auto G  = [&](int i) { return (const float*)d_in[1 + (i - 1) * 6 + 2]; };
    auto Be = [&](int i) { return (const float*)d_in[1 + (i - 1) * 6 + 3]; };
    auto M  = [&](int i) { return (const float*)d_in[1 + (i - 1) * 6 + 4]; };
    auto V  = [&](int i) { return (const float*)d_in[1 + (i - 1) * 6 + 5]; };
    const float* fw1 = (const float*)d_in[37];
    const float* fb1 = (const float*)d_in[38];
    const float* fw2 = (const float*)d_in[39];
    const float* fb2 = (const float*)d_in[40];
    const float* fw3 = (const float*)d_in[41];
    const float* fb3 = (const float*)d_in[42];
    float* out = (float*)d_out;

    // Per-sample workspace need (fp32 elements):
    //   buf0: max(L1 out 128*30*30=115200, L3 out 256*12*12=36864, FC outs) = 115200
    //   buf1: max(L2 out 128*14*14=25088, L4 out 256*5*5=6400, ...)          = 25088
    const long long B0_PER = 115200, B1_PER = 25088;
    const long long need_per_b = (B0_PER + B1_PER) * (long long)sizeof(float); // 561,152 B

    // Largest power-of-two chunk of the batch that fits in ws_size.
    int Bc = B;
    while (Bc > 1 && (long long)Bc * need_per_b > (long long)ws_size) Bc >>= 1;

    const int TB = 256;

    for (int b0 = 0; b0 < B; b0 += Bc) {
        float* buf0 = (float*)d_ws;
        float* buf1 = buf0 + (long long)Bc * B0_PER;

        const float* xc = x + (long long)b0 * 3 * 32 * 32;
        long long n;

        // L1: [Bc,3,32,32] -> [Bc,128,30,30]
        n = (long long)Bc * 128 * 30 * 30;
        conv_bn_relu_kernel<3, false><<<cdiv_ll(n, TB), TB, 0, stream>>>(
            xc, W(1), Bi(1), G(1), Be(1), M(1), V(1), buf0, Bc, 128, 32, 32);

        // L2: -> [Bc,128,28,28] -> pool -> [Bc,128,14,14]
        n = (long long)Bc * 128 * 14 * 14;
        conv_bn_relu_kernel<128, true><<<cdiv_ll(n, TB), TB, 0, stream>>>(
            buf0, W(2), Bi(2), G(2), Be(2), M(2), V(2), buf1, Bc, 128, 30, 30);

        // L3: -> [Bc,256,12,12]
        n = (long long)Bc * 256 * 12 * 12;
        conv_bn_relu_kernel<128, false><<<cdiv_ll(n, TB), TB, 0, stream>>>(
            buf1, W(3), Bi(3), G(3), Be(3), M(3), V(3), buf0, Bc, 256, 14, 14);

        // L4: -> [Bc,256,10,10] -> pool -> [Bc,256,5,5]
        n = (long long)Bc * 256 * 5 * 5;
        conv_bn_relu_kernel<256, true><<<cdiv_ll(n, TB), TB, 0, stream>>>(
            buf0, W(4), Bi(4), G(4), Be(4), M(4), V(4), buf1, Bc, 256, 12, 12);

        // L5: -> [Bc,512,3,3]
        n = (long long)Bc * 512 * 3 * 3;
        conv_bn_relu_kernel<256, false><<<cdiv_ll(n, TB), TB, 0, stream>>>(
            buf1, W(5), Bi(5), G(5), Be(5), M(5), V(5), buf0, Bc, 512, 5, 5);

        // L6: -> [Bc,512,1,1]
        n = (long long)Bc * 512 * 1 * 1;
        conv_bn_relu_kernel<512, false><<<cdiv_ll(n, TB), TB, 0, stream>>>(
            buf0, W(6), Bi(6), G(6), Be(6), M(6), V(6), buf1, Bc, 512, 3, 3);

        // FC1: [Bc,512] -> [Bc,1024], relu
        n = (long long)Bc * 1024;
        fc_kernel<<<cdiv_ll(n, TB), TB, 0, stream>>>(buf1, fw1, fb1, buf0, Bc, 512, 1024, 1);
        // FC2: [Bc,1024] -> [Bc,1024], relu
        fc_kernel<<<cdiv_ll(n, TB), TB, 0, stream>>>(buf0, fw2, fb2, buf1, Bc, 1024, 1024, 1);
        // FC3: [Bc,1024] -> [Bc,10], logits
        n = (long long)Bc * 10;
        fc_kernel<<<cdiv_ll(n, TB), TB, 0, stream>>>(buf1, fw3, fb3, buf0, Bc, 1024, 10, 0);

        // softmax rows of 10 -> d_out (chunk offset)
        softmax10_kernel<<<cdiv_ll(Bc, TB), TB, 0, stream>>>(buf0, out + (long long)b0 * 10, Bc);
    }
}